// Round 1
// baseline (11075.890 us; speedup 1.0000x reference)
//
#include <hip/hip_runtime.h>

#define B_ 64
#define H_ 1024
#define V_ 32000
#define T_ 64
#define BN 64
#define NBLK (V_/BN)   /* 500 */
#define MARGIN 1e-3f
#define CAND_MAX 128

typedef short bf16x8 __attribute__((ext_vector_type(8)));
typedef float f32x4 __attribute__((ext_vector_type(4)));

__device__ __forceinline__ unsigned short f2bf(float f) {
  unsigned int u = __float_as_uint(f);
  u += 0x7fffu + ((u >> 16) & 1u);          // RNE to bf16
  return (unsigned short)(u >> 16);
}
__device__ __forceinline__ float bf2f(unsigned short s) {
  return __uint_as_float(((unsigned int)s) << 16);
}

// ---------------- one-time: split W_out into bf16 hi/lo ----------------
__global__ __launch_bounds__(256) void split_w_kernel(
    const float4* __restrict__ W, ushort4* __restrict__ hi, ushort4* __restrict__ lo)
{
  const int n4 = V_ * H_ / 4;
  int idx = blockIdx.x * 256 + threadIdx.x;
  int stride = gridDim.x * 256;
  for (int i = idx; i < n4; i += stride) {
    float4 w = W[i];
    ushort4 h, l;
    h.x = f2bf(w.x); l.x = f2bf(w.x - bf2f(h.x));
    h.y = f2bf(w.y); l.y = f2bf(w.y - bf2f(h.y));
    h.z = f2bf(w.z); l.z = f2bf(w.z - bf2f(h.z));
    h.w = f2bf(w.w); l.w = f2bf(w.w - bf2f(h.w));
    hi[i] = h; lo[i] = l;
  }
}

__global__ void decoder_init(const int* __restrict__ x, int* __restrict__ tokbuf) {
  int i = threadIdx.x;
  if (i < B_) tokbuf[i] = x[i];   // x is (B,1)
}

// ---------------- per step: hidden state (fp32 VALU) ----------------
// grid 256 = 64 j-tiles(16) x 4 b-tiles(16); block 256 = 16j x 16b
__global__ __launch_bounds__(256) void decoder_hidden(
    const int* __restrict__ tok, const float* __restrict__ hprev,
    const float* __restrict__ emb, const float* __restrict__ Wih,
    const float* __restrict__ bih, const float* __restrict__ Whh,
    const float* __restrict__ bhh,
    float* __restrict__ hnf, unsigned short* __restrict__ hnhi,
    unsigned short* __restrict__ hnlo, float* __restrict__ hseq_t)
{
  const int tid = threadIdx.x;
  const int jt = blockIdx.x & 63, bt = blockIdx.x >> 6;
  const int j = jt * 16 + (tid & 15);
  const int b = bt * 16 + (tid >> 4);
  const int tk = tok[b];
  const float4* wi = (const float4*)(Wih + (size_t)j * H_);
  const float4* wh = (const float4*)(Whh + (size_t)j * H_);
  const float4* ev = (const float4*)(emb + (size_t)tk * H_);
  const float4* hv = (const float4*)(hprev + (size_t)b * H_);
  float a0=0,a1=0,a2=0,a3=0, c0=0,c1=0,c2=0,c3=0;
  #pragma unroll 4
  for (int k = 0; k < H_/4; ++k) {
    float4 e4 = ev[k]; float4 w4 = wi[k];
    float4 h4 = hv[k]; float4 g4 = wh[k];
    a0 += fmaxf(e4.x,0.f)*w4.x; a1 += fmaxf(e4.y,0.f)*w4.y;
    a2 += fmaxf(e4.z,0.f)*w4.z; a3 += fmaxf(e4.w,0.f)*w4.w;
    c0 += h4.x*g4.x; c1 += h4.y*g4.y; c2 += h4.z*g4.z; c3 += h4.w*g4.w;
  }
  float dA = (a0+a1)+(a2+a3);
  float dB = (c0+c1)+(c2+c3);
  float v = tanhf(((dA + bih[j]) + dB) + bhh[j]);
  const int o = b * H_ + j;
  hnf[o] = v;
  unsigned short hi = f2bf(v);
  hnhi[o] = hi;
  hnlo[o] = f2bf(v - bf2f(hi));
  hseq_t[o] = v;
}

// ---------------- per step: logits GEMM (split-bf16 MFMA) ----------------
// grid NBLK(500) blocks of 64 n; block 256 = 4 waves, wave = 64b x 16n
// y[b][n] = sum_k hn[b][k]*W[n][k] + b_out[n]  via mfma(A=hn rows, B=W rows)
template<int SPLIT>
__global__ __launch_bounds__(256) void decoder_logits(
    const unsigned short* __restrict__ Whi, const unsigned short* __restrict__ Wlo,
    const float* __restrict__ Wout,
    const unsigned short* __restrict__ hnhi, const unsigned short* __restrict__ hnlo,
    const float* __restrict__ bout,
    float* __restrict__ logits, float* __restrict__ bmax, int t)
{
  const int tid = threadIdx.x;
  const int w = tid >> 6, l = tid & 63;
  const int ln = l & 15, kq = l >> 4;
  const int n0 = blockIdx.x * BN + w * 16;
  const int nr = n0 + ln;                 // W row / output col this lane touches

  f32x4 acc[4] = {{0.f,0.f,0.f,0.f},{0.f,0.f,0.f,0.f},{0.f,0.f,0.f,0.f},{0.f,0.f,0.f,0.f}};

  #pragma unroll 2
  for (int kt = 0; kt < H_/32; ++kt) {
    const int kof = kt * 32 + kq * 8;
    bf16x8 bh, bl;
    if (SPLIT) {
      bh = *(const bf16x8*)(Whi + (size_t)nr * H_ + kof);
      bl = *(const bf16x8*)(Wlo + (size_t)nr * H_ + kof);
    } else {
      const float* wr = Wout + (size_t)nr * H_ + kof;
      float4 wa = *(const float4*)wr;
      float4 wb = *(const float4*)(wr + 4);
      float wv[8] = {wa.x,wa.y,wa.z,wa.w,wb.x,wb.y,wb.z,wb.w};
      #pragma unroll
      for (int i = 0; i < 8; ++i) {
        unsigned short h = f2bf(wv[i]);
        bh[i] = (short)h;
        bl[i] = (short)f2bf(wv[i] - bf2f(h));
      }
    }
    #pragma unroll
    for (int m = 0; m < 4; ++m) {
      bf16x8 ah = *(const bf16x8*)(hnhi + (size_t)(m*16 + ln) * H_ + kof);
      bf16x8 al = *(const bf16x8*)(hnlo + (size_t)(m*16 + ln) * H_ + kof);
      acc[m] = __builtin_amdgcn_mfma_f32_16x16x32_bf16(ah, bh, acc[m], 0, 0, 0);
      acc[m] = __builtin_amdgcn_mfma_f32_16x16x32_bf16(ah, bl, acc[m], 0, 0, 0);
      acc[m] = __builtin_amdgcn_mfma_f32_16x16x32_bf16(al, bh, acc[m], 0, 0, 0);
    }
  }

  // epilogue: C/D lane map (16x16): col = l&15 (= n), row = (l>>4)*4 + r (= b within m-tile)
  __shared__ float pmax[4][B_];
  const float bo = bout[nr];
  #pragma unroll
  for (int m = 0; m < 4; ++m) {
    #pragma unroll
    for (int r = 0; r < 4; ++r) {
      float v = acc[m][r] + bo;
      const int brow = m * 16 + kq * 4 + r;
      logits[((size_t)brow * T_ + t) * V_ + n0 + ln] = v;
      float mx = v;
      mx = fmaxf(mx, __shfl_xor(mx, 1));
      mx = fmaxf(mx, __shfl_xor(mx, 2));
      mx = fmaxf(mx, __shfl_xor(mx, 4));
      mx = fmaxf(mx, __shfl_xor(mx, 8));
      if (ln == 0) pmax[w][brow] = mx;
    }
  }
  __syncthreads();
  if (tid < B_) {
    float mm = fmaxf(fmaxf(pmax[0][tid], pmax[1][tid]),
                     fmaxf(pmax[2][tid], pmax[3][tid]));
    bmax[(size_t)tid * NBLK + blockIdx.x] = mm;
  }
}

// ---------------- per step: exact-fp32-refined argmax + feedback ----------------
// grid 64 (one block per batch row), block 256
__global__ __launch_bounds__(256) void decoder_argmax(
    const float* __restrict__ bmax, const float* __restrict__ logits,
    const float* __restrict__ hnf, const float* __restrict__ Wout,
    const float* __restrict__ bout,
    int* __restrict__ tokbuf, float* __restrict__ preds, int t)
{
  const int b = blockIdx.x;
  const int tid = threadIdx.x;
  const int w = tid >> 6, l = tid & 63;
  __shared__ float wred[4];
  __shared__ int ncand;
  __shared__ int   cand_n[CAND_MAX];
  __shared__ float cand_v[CAND_MAX];

  float m = -3.4e38f;
  for (int i = tid; i < NBLK; i += 256) m = fmaxf(m, bmax[(size_t)b * NBLK + i]);
  #pragma unroll
  for (int s = 1; s < 64; s <<= 1) m = fmaxf(m, __shfl_xor(m, s));
  if (l == 0) wred[w] = m;
  if (tid == 0) ncand = 0;
  __syncthreads();
  const float gm = fmaxf(fmaxf(wred[0], wred[1]), fmaxf(wred[2], wred[3]));
  const float th = gm - MARGIN;

  const float* lrow = logits + ((size_t)b * T_ + t) * V_;
  for (int i = tid; i < NBLK; i += 256) {
    if (bmax[(size_t)b * NBLK + i] >= th) {
      const float* seg = lrow + i * BN;
      for (int q = 0; q < BN; ++q) {
        float v = seg[q];
        if (v >= th) {
          int pos = atomicAdd(&ncand, 1);
          if (pos < CAND_MAX) cand_n[pos] = i * BN + q;
        }
      }
    }
  }
  __syncthreads();
  int nc = ncand; nc = nc < CAND_MAX ? nc : CAND_MAX;
  const float* hrow = hnf + (size_t)b * H_;
  for (int ci = w; ci < nc; ci += 4) {
    const int n = cand_n[ci];
    const float* wrow = Wout + (size_t)n * H_;
    float a = 0.f;
    for (int k = l; k < H_; k += 64) a += hrow[k] * wrow[k];
    #pragma unroll
    for (int s = 1; s < 64; s <<= 1) a += __shfl_xor(a, s);
    if (l == 0) cand_v[ci] = a + bout[n];
  }
  __syncthreads();
  if (tid == 0) {
    float bv = -3.4e38f; int bn = 0x7fffffff;
    for (int ci = 0; ci < nc; ++ci) {
      float v = cand_v[ci]; int n = cand_n[ci];
      if (v > bv || (v == bv && n < bn)) { bv = v; bn = n; }
    }
    tokbuf[b] = bn;
    preds[(size_t)b * T_ + t] = (float)bn;
  }
}

extern "C" void kernel_launch(void* const* d_in, const int* in_sizes, int n_in,
                              void* d_out, int out_size, void* d_ws, size_t ws_size,
                              hipStream_t stream) {
  const int*   x    = (const int*)d_in[0];
  const float* h0   = (const float*)d_in[1];
  const float* emb  = (const float*)d_in[3];
  const float* Wih  = (const float*)d_in[4];
  const float* bih  = (const float*)d_in[5];
  const float* Whh  = (const float*)d_in[6];
  const float* bhh  = (const float*)d_in[7];
  const float* Wout = (const float*)d_in[8];
  const float* bout = (const float*)d_in[9];

  float* out    = (float*)d_out;
  float* logits = out;                                   // [B][T][V]
  float* preds  = out + (size_t)B_ * T_ * V_;            // [B][T] as float
  float* hseq   = preds + (size_t)B_ * T_;               // [T][B][H]

  size_t cur = 0;
  char* wsb = (char*)d_ws;
  auto alloc = [&](size_t bytes) -> char* {
    char* p = wsb + cur; cur += (bytes + 255) & ~(size_t)255; return p;
  };
  int*            tokbuf = (int*)           alloc((size_t)B_ * sizeof(int));
  float*          bmax   = (float*)         alloc((size_t)B_ * NBLK * sizeof(float));
  float*          hnf0   = (float*)         alloc((size_t)B_ * H_ * sizeof(float));
  float*          hnf1   = (float*)         alloc((size_t)B_ * H_ * sizeof(float));
  unsigned short* hnhi   = (unsigned short*)alloc((size_t)B_ * H_ * 2);
  unsigned short* hnlo   = (unsigned short*)alloc((size_t)B_ * H_ * 2);
  unsigned short* Whi    = (unsigned short*)alloc((size_t)V_ * H_ * 2);
  unsigned short* Wlo    = (unsigned short*)alloc((size_t)V_ * H_ * 2);
  const bool split = (cur <= ws_size);

  if (split)
    split_w_kernel<<<2048, 256, 0, stream>>>((const float4*)Wout, (ushort4*)Whi, (ushort4*)Wlo);
  decoder_init<<<1, 64, 0, stream>>>(x, tokbuf);

  for (int t = 0; t < T_; ++t) {
    float* hcur = (t & 1) ? hnf1 : hnf0;
    const float* hprev = (t == 0) ? h0 : ((t & 1) ? hnf0 : hnf1);
    decoder_hidden<<<256, 256, 0, stream>>>(tokbuf, hprev, emb, Wih, bih, Whh, bhh,
                                            hcur, hnhi, hnlo,
                                            hseq + (size_t)t * B_ * H_);
    if (split)
      decoder_logits<1><<<NBLK, 256, 0, stream>>>(Whi, Wlo, Wout, hnhi, hnlo, bout,
                                                  logits, bmax, t);
    else
      decoder_logits<0><<<NBLK, 256, 0, stream>>>(Whi, Wlo, Wout, hnhi, hnlo, bout,
                                                  logits, bmax, t);
    decoder_argmax<<<B_, 256, 0, stream>>>(bmax, logits, hcur, Wout, bout,
                                           tokbuf, preds, t);
  }
}

// Round 2
// 8597.835 us; speedup vs baseline: 1.2882x; 1.2882x over previous
//
#include <hip/hip_runtime.h>

#define B_ 64
#define H_ 1024
#define V_ 32000
#define T_ 64
#define BN 64
#define NBLK (V_/BN)   /* 500 */
#define MARGIN 2e-2f
#define CAND_MAX 128
#define SEG_MAX 64

typedef short bf16x8 __attribute__((ext_vector_type(8)));
typedef float f32x4 __attribute__((ext_vector_type(4)));

__device__ __forceinline__ unsigned short f2bf(float f) {
  unsigned int u = __float_as_uint(f);
  u += 0x7fffu + ((u >> 16) & 1u);          // RNE to bf16
  return (unsigned short)(u >> 16);
}
__device__ __forceinline__ float bf2f(unsigned short s) {
  return __uint_as_float(((unsigned int)s) << 16);
}

// ---------------- one-time: W_out -> bf16 (hi only) ----------------
__global__ __launch_bounds__(256) void split_w_kernel(
    const float4* __restrict__ W, ushort4* __restrict__ hi)
{
  const int n4 = V_ * H_ / 4;
  int idx = blockIdx.x * 256 + threadIdx.x;
  int stride = gridDim.x * 256;
  for (int i = idx; i < n4; i += stride) {
    float4 w = W[i];
    ushort4 h;
    h.x = f2bf(w.x); h.y = f2bf(w.y); h.z = f2bf(w.z); h.w = f2bf(w.w);
    hi[i] = h;
  }
}

__global__ void decoder_init(const int* __restrict__ x, int* __restrict__ tokbuf) {
  int i = threadIdx.x;
  if (i < B_) tokbuf[i] = x[i];   // x is (B,1)
}

// ---------------- per step: hidden state (fp32 VALU) ----------------
// NUMERICS-LOCKED: identical FP op order to the R0 passing version.
// grid 256 = 64 j-tiles(16) x 4 b-tiles(16); block 256 = 16j x 16b
__global__ __launch_bounds__(256) void decoder_hidden(
    const int* __restrict__ tok, const float* __restrict__ hprev,
    const float* __restrict__ emb, const float* __restrict__ Wih,
    const float* __restrict__ bih, const float* __restrict__ Whh,
    const float* __restrict__ bhh,
    float* __restrict__ hnf, unsigned short* __restrict__ hnhi,
    float* __restrict__ hseq_t)
{
  const int tid = threadIdx.x;
  const int jt = blockIdx.x & 63, bt = blockIdx.x >> 6;
  const int j = jt * 16 + (tid & 15);
  const int b = bt * 16 + (tid >> 4);
  const int tk = tok[b];
  const float4* wi = (const float4*)(Wih + (size_t)j * H_);
  const float4* wh = (const float4*)(Whh + (size_t)j * H_);
  const float4* ev = (const float4*)(emb + (size_t)tk * H_);
  const float4* hv = (const float4*)(hprev + (size_t)b * H_);
  float a0=0,a1=0,a2=0,a3=0, c0=0,c1=0,c2=0,c3=0;
  #pragma unroll 4
  for (int k = 0; k < H_/4; ++k) {
    float4 e4 = ev[k]; float4 w4 = wi[k];
    float4 h4 = hv[k]; float4 g4 = wh[k];
    a0 += fmaxf(e4.x,0.f)*w4.x; a1 += fmaxf(e4.y,0.f)*w4.y;
    a2 += fmaxf(e4.z,0.f)*w4.z; a3 += fmaxf(e4.w,0.f)*w4.w;
    c0 += h4.x*g4.x; c1 += h4.y*g4.y; c2 += h4.z*g4.z; c3 += h4.w*g4.w;
  }
  float dA = (a0+a1)+(a2+a3);
  float dB = (c0+c1)+(c2+c3);
  float v = tanhf(((dA + bih[j]) + dB) + bhh[j]);
  const int o = b * H_ + j;
  hnf[o] = v;
  hnhi[o] = f2bf(v);
  hseq_t[o] = v;
}

// ---------------- per step: logits GEMM (bf16-hi 1-pass MFMA) ----------------
// grid NBLK(500); block 256 = 4 waves; wave = 64b x 16n (4 m-tiles of 16x16x32)
// y[b][n] = sum_k hn[b][k]*W[n][k] + b_out[n]
template<int SPLIT>
__global__ __launch_bounds__(256) void decoder_logits(
    const unsigned short* __restrict__ Whi, const float* __restrict__ Wout,
    const unsigned short* __restrict__ hnhi, const float* __restrict__ bout,
    float* __restrict__ logits, float* __restrict__ bmax, int t)
{
  const int tid = threadIdx.x;
  const int w = tid >> 6, l = tid & 63;
  const int ln = l & 15, kq = l >> 4;
  const int n0 = blockIdx.x * BN + w * 16;
  const int nr = n0 + ln;                 // W row / output col this lane touches

  f32x4 acc[4] = {{0.f,0.f,0.f,0.f},{0.f,0.f,0.f,0.f},{0.f,0.f,0.f,0.f},{0.f,0.f,0.f,0.f}};

  const bf16x8* wp = (const bf16x8*)(Whi + (size_t)nr * H_) + kq; // stride 4 per kt
  bf16x8 b_cur;
  if (SPLIT) {
    b_cur = wp[0];
  } else {
    const float* wr = Wout + (size_t)nr * H_ + kq * 8;
    float4 wa = *(const float4*)wr, wb = *(const float4*)(wr + 4);
    float wv[8] = {wa.x,wa.y,wa.z,wa.w,wb.x,wb.y,wb.z,wb.w};
    #pragma unroll
    for (int i = 0; i < 8; ++i) b_cur[i] = (short)f2bf(wv[i]);
  }

  #pragma unroll 4
  for (int kt = 0; kt < H_/32; ++kt) {
    // branchless depth-1 prefetch of next B fragment (clamped index, stays in-bounds)
    const int ktn = (kt < 31) ? (kt + 1) : kt;
    bf16x8 b_nxt;
    if (SPLIT) {
      b_nxt = wp[ktn * 4];
    } else {
      const float* wr = Wout + (size_t)nr * H_ + ktn * 32 + kq * 8;
      float4 wa = *(const float4*)wr, wb = *(const float4*)(wr + 4);
      float wv[8] = {wa.x,wa.y,wa.z,wa.w,wb.x,wb.y,wb.z,wb.w};
      #pragma unroll
      for (int i = 0; i < 8; ++i) b_nxt[i] = (short)f2bf(wv[i]);
    }
    const int kof = kt * 32 + kq * 8;
    #pragma unroll
    for (int m = 0; m < 4; ++m) {
      bf16x8 ah = *(const bf16x8*)(hnhi + (size_t)(m*16 + ln) * H_ + kof);
      acc[m] = __builtin_amdgcn_mfma_f32_16x16x32_bf16(ah, b_cur, acc[m], 0, 0, 0);
    }
    b_cur = b_nxt;
  }

  // epilogue: C/D lane map (16x16): col = l&15 (= n), row = (l>>4)*4 + r (= b)
  __shared__ float pmax[4][B_];
  const float bo = bout[nr];
  #pragma unroll
  for (int m = 0; m < 4; ++m) {
    #pragma unroll
    for (int r = 0; r < 4; ++r) {
      float v = acc[m][r] + bo;
      const int brow = m * 16 + kq * 4 + r;
      logits[((size_t)brow * T_ + t) * V_ + n0 + ln] = v;
      float mx = v;
      mx = fmaxf(mx, __shfl_xor(mx, 1));
      mx = fmaxf(mx, __shfl_xor(mx, 2));
      mx = fmaxf(mx, __shfl_xor(mx, 4));
      mx = fmaxf(mx, __shfl_xor(mx, 8));
      if (ln == 0) pmax[w][brow] = mx;
    }
  }
  __syncthreads();
  if (tid < B_) {
    float mm = fmaxf(fmaxf(pmax[0][tid], pmax[1][tid]),
                     fmaxf(pmax[2][tid], pmax[3][tid]));
    bmax[(size_t)tid * NBLK + blockIdx.x] = mm;
  }
}

// ---------------- per step: exact-fp32-refined argmax + feedback ----------------
// grid 64 (one block per batch row), block 256
__global__ __launch_bounds__(256) void decoder_argmax(
    const float* __restrict__ bmax, const float* __restrict__ logits,
    const float* __restrict__ hnf, const float* __restrict__ Wout,
    const float* __restrict__ bout,
    int* __restrict__ tokbuf, float* __restrict__ preds, int t)
{
  const int b = blockIdx.x;
  const int tid = threadIdx.x;
  const int w = tid >> 6, l = tid & 63;
  __shared__ float wred[4];
  __shared__ int nseg, ncand;
  __shared__ int   seglist[SEG_MAX];
  __shared__ int   cand_n[CAND_MAX];
  __shared__ float cand_v[CAND_MAX];

  if (tid == 0) { nseg = 0; ncand = 0; }
  const float* brow = bmax + (size_t)b * NBLK;
  float m = -3.4e38f;
  for (int i = tid; i < NBLK; i += 256) m = fmaxf(m, brow[i]);
  #pragma unroll
  for (int s = 1; s < 64; s <<= 1) m = fmaxf(m, __shfl_xor(m, s));
  if (l == 0) wred[w] = m;
  __syncthreads();
  const float gm = fmaxf(fmaxf(wred[0], wred[1]), fmaxf(wred[2], wred[3]));
  const float th = gm - MARGIN;

  // collect passing segments (usually 1-2)
  for (int i = tid; i < NBLK; i += 256) {
    if (brow[i] >= th) {
      int pos = atomicAdd(&nseg, 1);
      if (pos < SEG_MAX) seglist[pos] = i;
    }
  }
  __syncthreads();
  const int ns = nseg < SEG_MAX ? nseg : SEG_MAX;

  // parallel scan: 4 segments at a time, 64 lanes each (BN==64)
  const float* lrow = logits + ((size_t)b * T_ + t) * V_;
  for (int s = w; s < ns; s += 4) {
    const int seg = seglist[s];
    float v = lrow[seg * BN + l];
    if (v >= th) {
      int pos = atomicAdd(&ncand, 1);
      if (pos < CAND_MAX) cand_n[pos] = seg * BN + l;
    }
  }
  __syncthreads();
  int nc = ncand; nc = nc < CAND_MAX ? nc : CAND_MAX;

  // exact fp32 rescore of candidates
  const float* hrow = hnf + (size_t)b * H_;
  for (int ci = w; ci < nc; ci += 4) {
    const int n = cand_n[ci];
    const float* wrow = Wout + (size_t)n * H_;
    float a = 0.f;
    for (int k = l; k < H_; k += 64) a += hrow[k] * wrow[k];
    #pragma unroll
    for (int s = 1; s < 64; s <<= 1) a += __shfl_xor(a, s);
    if (l == 0) cand_v[ci] = a + bout[n];
  }
  __syncthreads();
  if (tid == 0) {
    float bv = -3.4e38f; int bn = 0x7fffffff;
    for (int ci = 0; ci < nc; ++ci) {
      float v = cand_v[ci]; int n = cand_n[ci];
      if (v > bv || (v == bv && n < bn)) { bv = v; bn = n; }
    }
    tokbuf[b] = bn;
    preds[(size_t)b * T_ + t] = (float)bn;
  }
}

extern "C" void kernel_launch(void* const* d_in, const int* in_sizes, int n_in,
                              void* d_out, int out_size, void* d_ws, size_t ws_size,
                              hipStream_t stream) {
  const int*   x    = (const int*)d_in[0];
  const float* h0   = (const float*)d_in[1];
  const float* emb  = (const float*)d_in[3];
  const float* Wih  = (const float*)d_in[4];
  const float* bih  = (const float*)d_in[5];
  const float* Whh  = (const float*)d_in[6];
  const float* bhh  = (const float*)d_in[7];
  const float* Wout = (const float*)d_in[8];
  const float* bout = (const float*)d_in[9];

  float* out    = (float*)d_out;
  float* logits = out;                                   // [B][T][V]
  float* preds  = out + (size_t)B_ * T_ * V_;            // [B][T] as float
  float* hseq   = preds + (size_t)B_ * T_;               // [T][B][H]

  size_t cur = 0;
  char* wsb = (char*)d_ws;
  auto alloc = [&](size_t bytes) -> char* {
    char* p = wsb + cur; cur += (bytes + 255) & ~(size_t)255; return p;
  };
  int*            tokbuf = (int*)           alloc((size_t)B_ * sizeof(int));
  float*          bmax   = (float*)         alloc((size_t)B_ * NBLK * sizeof(float));
  float*          hnf0   = (float*)         alloc((size_t)B_ * H_ * sizeof(float));
  float*          hnf1   = (float*)         alloc((size_t)B_ * H_ * sizeof(float));
  unsigned short* hnhi   = (unsigned short*)alloc((size_t)B_ * H_ * 2);
  unsigned short* Whi    = (unsigned short*)alloc((size_t)V_ * H_ * 2);
  const bool split = (cur <= ws_size);

  if (split)
    split_w_kernel<<<2048, 256, 0, stream>>>((const float4*)Wout, (ushort4*)Whi);
  decoder_init<<<1, 64, 0, stream>>>(x, tokbuf);

  for (int t = 0; t < T_; ++t) {
    float* hcur = (t & 1) ? hnf1 : hnf0;
    const float* hprev = (t == 0) ? h0 : ((t & 1) ? hnf0 : hnf1);
    decoder_hidden<<<256, 256, 0, stream>>>(tokbuf, hprev, emb, Wih, bih, Whh, bhh,
                                            hcur, hnhi,
                                            hseq + (size_t)t * B_ * H_);
    if (split)
      decoder_logits<1><<<NBLK, 256, 0, stream>>>(Whi, Wout, hnhi, bout,
                                                  logits, bmax, t);
    else
      decoder_logits<0><<<NBLK, 256, 0, stream>>>(Whi, Wout, hnhi, bout,
                                                  logits, bmax, t);
    decoder_argmax<<<B_, 256, 0, stream>>>(bmax, logits, hcur, Wout, bout,
                                           tokbuf, preds, t);
  }
}